// Round 13
// baseline (226.402 us; speedup 1.0000x reference)
//
#include <hip/hip_runtime.h>

// CombinedActorModel R17: R12b + direct-store epilogue + no-max softmax.
// Scoreboard: only instruction-count cuts have ever paid (R12b -9us); all
// scheduling levers (R13 ILP, R14 hoist, R15 residency, R16 TA-coalesce) are
// null-to-negative. R17 takes the two remaining safe cuts:
// 1) epilogue stores go DIRECT to global (lane(e,q) holds ch4q..4q+3 ->
//    q<2: float4 @ out[elem*9+4q] (4-aligned store), q==2: ch8 scalar).
//    Deletes the lds_o compaction (~10 DS ops/tile + DS round-trip + the
//    262K bank conflicts from the 36B-stride writes).
// 2) softmax drops the max-subtraction: gates bounded (|g|<~5.2, exp<200,
//    f32 safe) -> saves 2 fmax + 3 sub on the serial chain.
// Everything else byte-identical to R12b (cvt_pkrtz packs, bias folded into
// spare K-slots, LDS frag image + pinned-index ds_read_b128, ping-pong
// spatial prefetch, 512-thread blocks, TPB=4, grid 2048).

typedef _Float16 half8   __attribute__((ext_vector_type(8)));
typedef __fp16   fp16x2  __attribute__((ext_vector_type(2)));
typedef float    floatx4 __attribute__((ext_vector_type(4)));
typedef float    f4u     __attribute__((ext_vector_type(4), aligned(4)));

#define NFRAG 21                    // 3 actors * (4 stage1 + 2 stage2 + 1 stage3)
#define FRAG_HALFS (NFRAG * 512)    // 10752 halfs = 21504 B
#define TPB 4                       // tiles per block (tile = 128 elements)
#define NWAVES 8                    // 512-thread blocks

__global__ __launch_bounds__(256) void prep_frags(
    const float* __restrict__ Wmx, const float* __restrict__ bmx,
    const float* __restrict__ Wnx, const float* __restrict__ bnx,
    const float* __restrict__ Wmy, const float* __restrict__ bmy,
    const float* __restrict__ Wny, const float* __restrict__ bny,
    const float* __restrict__ Wmz, const float* __restrict__ bmz,
    const float* __restrict__ Wnz, const float* __restrict__ bnz,
    const float* __restrict__ Wlin, const float* __restrict__ blin,
    const float* __restrict__ Wout, const float* __restrict__ bout,
    _Float16* __restrict__ frag)
{
    int i = threadIdx.x + blockIdx.x * blockDim.x;
    if (i >= FRAG_HALFS) return;
    int f = i >> 9, rem = i & 511;
    int lane = rem >> 3, j = rem & 7;
    int q = lane >> 4, m = lane & 15;
    int a = f / 7, idx = f % 7;
    float v = 0.f;
    if (idx < 4) {
        int c = m + ((idx & 1) ? 16 : 0);
        int k = 8 * q + j;
        bool npart = (idx >= 2);
        if (c < 10) {
            if (!npart) { if (k < 6)             v = Wmx[(a*10 + c)*6 + k];
                          else if (k == 27)      v = bmx[a*10 + c]; }
            else        { if (k >= 6 && k < 9)   v = Wnx[(a*10 + c)*3 + (k-6)];
                          else if (k == 27)      v = bnx[a*10 + c]; }
        } else if (c < 20) {
            if (!npart) { if (k >= 9 && k < 15)  v = Wmy[(a*10 + c-10)*6 + (k-9)];
                          else if (k == 27)      v = bmy[a*10 + c-10]; }
            else        { if (k >= 15 && k < 18) v = Wny[(a*10 + c-10)*3 + (k-15)];
                          else if (k == 27)      v = bny[a*10 + c-10]; }
        } else if (c < 25) {
            if (!npart) { if (k >= 18 && k < 24) v = Wmz[(a*5 + c-20)*6 + (k-18)];
                          else if (k == 27)      v = bmz[a*5 + c-20]; }
            else        { if (k >= 24 && k < 27) v = Wnz[(a*5 + c-20)*3 + (k-24)];
                          else if (k == 27)      v = bnz[a*5 + c-20]; }
        }
    } else if (idx < 6) {
        int o  = m + ((idx == 5) ? 16 : 0);
        int kc = 16 * (j >> 2) + 4 * q + (j & 3);   // sigma(q,j)
        if (o < 25) {
            if (kc < 25)       v = Wlin[(a*25 + o)*25 + kc];
            else if (kc == 25) v = blin[a*25 + o];
        }
    } else {
        int ko = 16 * (j >> 2) + 4 * q + (j & 3);
        if (m < 10) {
            if (ko < 25)       v = Wout[(a*15 + m)*25 + ko];
            else if (ko == 25) v = bout[a*15 + m];
        }
    }
    frag[(size_t)f * 512 + lane * 8 + j] = (_Float16)v;
}

__global__ __launch_bounds__(512) void actor_mfma(
    const float* __restrict__ spatial,
    const _Float16* __restrict__ frag,
    float* __restrict__ out)
{
    __shared__ _Float16 lds_f[FRAG_HALFS];     // 21504 B, block-shared constants

    const int t = threadIdx.x;
    const int lane = t & 63, w = t >> 6;
    const int q = lane >> 4, e = lane & 15;
    const size_t b0 = (size_t)blockIdx.x * (16 * NWAVES * TPB);

    // ---- cooperative frag staging: 1344 float4, once per block
    {
        const float4* gf = (const float4*)frag;
        float4* df = (float4*)lds_f;
        #pragma unroll
        for (int k = 0; k < 3; ++k) {
            int idx = t + k * 512;
            if (idx < 1344) df[idx] = gf[idx];
        }
    }

    // ---- per-lane constants for the spatial gather (invariant across tiles)
    const float* sbase = spatial + (b0 + (size_t)(w * 16 + e)) * 27 + 8 * q;
    float vbase[8];
    #pragma unroll
    for (int j = 0; j < 8; ++j) vbase[j] = ((8 * q + j) == 27) ? 1.f : 0.f;

    const floatx4 z = {0.f, 0.f, 0.f, 0.f};

    __syncthreads();

    // 32-bit LDS half8-index; opaquely re-pinned per actor so the 21
    // loop-invariant ds_reads can't be hoisted into (and spill) registers.
    int fo = lane;

    auto loadT = [&](float (&dst)[8], int tt) {
        const float* s_ = sbase + (size_t)tt * (16 * NWAVES * 27);
        #pragma unroll
        for (int j = 0; j < 8; ++j) {
            int k = 8 * q + j;
            dst[j] = (k < 27) ? s_[j] : vbase[j];
        }
    };

    auto tileCompute = [&](const float (&cur)[8], int tt) {
        union H8u { half8 v; fp16x2 p[4]; };

        H8u Bs;
        #pragma unroll
        for (int p_ = 0; p_ < 4; ++p_)
            Bs.p[p_] = __builtin_amdgcn_cvt_pkrtz(cur[2*p_], cur[2*p_+1]);

        floatx4 oacc[3];
        #pragma unroll
        for (int a = 0; a < 3; ++a) {
            asm volatile("" : "+v"(fo));   // opaque: blocks LICM/clustering
            const half8* fp = (const half8*)lds_f + fo;
            const int fb = a * 7;
            // stage1: D[c][e]; ds_read_b128 at literal offsets feeds MFMA
            H8u P;
            {
                floatx4 M0 = __builtin_amdgcn_mfma_f32_16x16x32_f16(fp[(fb+0)*64], Bs.v, z, 0,0,0);
                floatx4 N0 = __builtin_amdgcn_mfma_f32_16x16x32_f16(fp[(fb+2)*64], Bs.v, z, 0,0,0);
                P.p[0] = __builtin_amdgcn_cvt_pkrtz(M0[0]*N0[0], M0[1]*N0[1]);
                P.p[1] = __builtin_amdgcn_cvt_pkrtz(M0[2]*N0[2], M0[3]*N0[3]);
            }
            {
                floatx4 M1 = __builtin_amdgcn_mfma_f32_16x16x32_f16(fp[(fb+1)*64], Bs.v, z, 0,0,0);
                floatx4 N1 = __builtin_amdgcn_mfma_f32_16x16x32_f16(fp[(fb+3)*64], Bs.v, z, 0,0,0);
                // sigma-packed slot kc=25 (q=2, elem 5) carries the stage2 bias
                float g5 = (q == 2) ? 1.f : M1[1]*N1[1];
                P.p[2] = __builtin_amdgcn_cvt_pkrtz(M1[0]*N1[0], g5);
                P.p[3] = __builtin_amdgcn_cvt_pkrtz(M1[2]*N1[2], M1[3]*N1[3]);
            }

            // stage2: D[o][e] (Wlin frag sigma-packed, bias at kc=25)
            floatx4 H0 = __builtin_amdgcn_mfma_f32_16x16x32_f16(fp[(fb+4)*64], P.v, z, 0,0,0);
            floatx4 H1 = __builtin_amdgcn_mfma_f32_16x16x32_f16(fp[(fb+5)*64], P.v, z, 0,0,0);

            // softsign -> packed B operand for stage3; bias column = 1.0
            auto ss = [](float v_) {
                return v_ * __builtin_amdgcn_rcpf(1.0f + __builtin_fabsf(v_));
            };
            H8u Hh;
            Hh.p[0] = __builtin_amdgcn_cvt_pkrtz(ss(H0[0]), ss(H0[1]));
            Hh.p[1] = __builtin_amdgcn_cvt_pkrtz(ss(H0[2]), ss(H0[3]));
            float h5 = (q == 2) ? 1.f : ss(H1[1]);
            Hh.p[2] = __builtin_amdgcn_cvt_pkrtz(ss(H1[0]), h5);
            Hh.p[3] = __builtin_amdgcn_cvt_pkrtz(ss(H1[2]), ss(H1[3]));

            // stage3: D[ch][e]; lane (e,q) reg r holds ch = 4q+r (gate ch9 @ q=2,r=1)
            oacc[a] = __builtin_amdgcn_mfma_f32_16x16x32_f16(fp[(fb+6)*64], Hh.v, z, 0,0,0);
        }

        // ---- epilogue: softmax over actors of ch9 (no max shift: |g|<~5.2),
        // weighted sum of ch0..8, DIRECT global stores (no LDS compaction)
        const int src9 = 32 + e;   // lane (e, q=2); its reg1 = ch9
        float g0 = __shfl(oacc[0][1], src9, 64);
        float g1 = __shfl(oacc[1][1], src9, 64);
        float g2 = __shfl(oacc[2][1], src9, 64);
        float e0 = __expf(g0);
        float e1 = __expf(g1);
        float e2 = __expf(g2);
        float inv = __builtin_amdgcn_rcpf(e0 + e1 + e2);
        e0 *= inv; e1 *= inv; e2 *= inv;

        float res[4];
        #pragma unroll
        for (int r = 0; r < 4; ++r)
            res[r] = oacc[0][r] * e0 + oacc[1][r] * e1 + oacc[2][r] * e2;

        float* po = out + (b0 + (size_t)tt * (16 * NWAVES) + w * 16 + e) * 9;
        if (q < 2) {
            f4u v4 = {res[0], res[1], res[2], res[3]};   // ch 4q..4q+3
            *(f4u*)(po + 4 * q) = v4;
        } else if (q == 2) {
            po[8] = res[0];                               // ch8
        }
    };

    // ---- software-pipelined tile loop: prefetch 1 tile ahead, ping-pong regs
    float sA[8], sB[8];
    loadT(sA, 0);
    for (int tt = 0; tt < TPB; tt += 2) {
        loadT(sB, tt + 1);
        tileCompute(sA, tt);
        if (tt + 2 < TPB) loadT(sA, tt + 2);
        tileCompute(sB, tt + 1);
    }
}

extern "C" void kernel_launch(void* const* d_in, const int* in_sizes, int n_in,
                              void* d_out, int out_size, void* d_ws, size_t ws_size,
                              hipStream_t stream) {
    const float* spatial = (const float*)d_in[0];
    // d_in[1] = car_stats: unused by the model, never read.
    const float* Wmx  = (const float*)d_in[2];
    const float* bmx  = (const float*)d_in[3];
    const float* Wnx  = (const float*)d_in[4];
    const float* bnx  = (const float*)d_in[5];
    const float* Wmy  = (const float*)d_in[6];
    const float* bmy  = (const float*)d_in[7];
    const float* Wny  = (const float*)d_in[8];
    const float* bny  = (const float*)d_in[9];
    const float* Wmz  = (const float*)d_in[10];
    const float* bmz  = (const float*)d_in[11];
    const float* Wnz  = (const float*)d_in[12];
    const float* bnz  = (const float*)d_in[13];
    const float* Wlin = (const float*)d_in[14];
    const float* blin = (const float*)d_in[15];
    const float* Wout = (const float*)d_in[16];
    const float* bout = (const float*)d_in[17];
    float* out = (float*)d_out;

    _Float16* frag = (_Float16*)d_ws;   // 21504 B

    prep_frags<<<dim3(42), dim3(256), 0, stream>>>(
        Wmx, bmx, Wnx, bnx, Wmy, bmy, Wny, bny, Wmz, bmz, Wnz, bnz,
        Wlin, blin, Wout, bout, frag);

    const int nb = in_sizes[0] / 27;           // 1048576, multiple of 16*NWAVES*TPB
    dim3 grid(nb / (16 * NWAVES * TPB));       // 2048 blocks, 8 waves each
    actor_mfma<<<grid, dim3(64 * NWAVES), 0, stream>>>(spatial, frag, out);
}